// Round 17
// baseline (744.858 us; speedup 1.0000x reference)
//
#include <hip/hip_runtime.h>

#define TTOK 4096
#define DDIM 1024
#define HDIM 4096
#define NEXP 64
#define CAP  512
#define NASN (TTOK*3)

typedef unsigned short u16;
typedef __attribute__((ext_vector_type(8))) short s16x8;
typedef __attribute__((ext_vector_type(4))) short s16x4;
typedef __attribute__((ext_vector_type(4))) float f32x4;

__device__ __forceinline__ u16 f2bf(float f) {
  union { float f; unsigned u; } v; v.f = f;
  unsigned u = v.u;
  return (u16)((u + 0x7fffu + ((u >> 16) & 1u)) >> 16);
}

__device__ __forceinline__ float bf2f(u16 h) {
  union { unsigned u; float f; } v; v.u = ((unsigned)h) << 16;
  return v.f;
}

__device__ __forceinline__ void gl_lds16(const void* g, void* l) {
  __builtin_amdgcn_global_load_lds(
      (const __attribute__((address_space(1))) void*)g,
      (__attribute__((address_space(3))) void*)l, 16, 0, 0);
}

// ---------------- gating: logits + top-3 + softmax ----------------
__global__ __launch_bounds__(512) void gate_topk(
    const float* __restrict__ x, const float* __restrict__ gw,
    const float* __restrict__ gb, int* __restrict__ fe, float* __restrict__ fg)
{
  int lane = threadIdx.x & 63;
  int wid  = threadIdx.x >> 6;
  int t = blockIdx.x * 8 + wid;
  const float* xr = x + (size_t)t * DDIM;
  float acc = gb[lane];
  #pragma unroll 4
  for (int d = 0; d < DDIM; d++) acc += xr[d] * gw[d * NEXP + lane];

  float v = acc;
  float bv[3]; int bi[3];
  #pragma unroll
  for (int j = 0; j < 3; j++) {
    float mv = v; int mi = lane;
    #pragma unroll
    for (int off = 32; off; off >>= 1) {
      float ov = __shfl_xor(mv, off);
      int   oi = __shfl_xor(mi, off);
      if (ov > mv || (ov == mv && oi < mi)) { mv = ov; mi = oi; }
    }
    bv[j] = mv; bi[j] = mi;
    if (lane == mi) v = -3.4e38f;
  }
  if (lane == 0) {
    float e1 = expf(bv[1] - bv[0]), e2 = expf(bv[2] - bv[0]);
    float inv = 1.0f / (1.0f + e1 + e2);
    fe[t*3+0] = bi[0]; fe[t*3+1] = bi[1]; fe[t*3+2] = bi[2];
    fg[t*3+0] = inv;   fg[t*3+1] = e1*inv; fg[t*3+2] = e2*inv;
  }
}

// ------- order-preserving per-expert slot assignment (exact ref semantics) -------
__global__ __launch_bounds__(64) void scan_pos(
    const int* __restrict__ fe, int* __restrict__ posA,
    int* __restrict__ s2a, int* __restrict__ cnt)
{
  int e = blockIdx.x, lane = threadIdx.x;
  int base = 0;
  for (int i0 = 0; i0 < NASN; i0 += 64) {
    int i = i0 + lane;
    bool m = (fe[i] == e);
    unsigned long long bal = __ballot(m);
    int below = __popcll(bal & ((1ull << lane) - 1ull));
    if (m) {
      int p = base + below;
      posA[i] = p;
      if (p < CAP) s2a[e * CAP + p] = i;
    }
    base += __popcll(bal);
  }
  if (lane == 0) cnt[e] = base < CAP ? base : CAP;
}

// ---------------- dispatch: scatter x rows into bf16 expert buffers ----------------
__global__ __launch_bounds__(64) void dispatch(
    const float* __restrict__ x, const int* __restrict__ fe,
    const int* __restrict__ posA, u16* __restrict__ bufA)
{
  int a = blockIdx.x;
  int p = posA[a];
  if (p >= CAP) return;
  int e = fe[a];
  int tok = a / 3;
  int l = threadIdx.x;
  const float4* xr = (const float4*)(x + (size_t)tok * DDIM);
  u16* dst = bufA + ((size_t)e * CAP + p) * DDIM;
  #pragma unroll
  for (int j = 0; j < 4; j++) {
    float4 v = xr[j * 64 + l];
    uint2 u;
    u.x = (unsigned)f2bf(v.x) | ((unsigned)f2bf(v.y) << 16);
    u.y = (unsigned)f2bf(v.z) | ((unsigned)f2bf(v.w) << 16);
    *(uint2*)(dst + (size_t)(j * 64 + l) * 4) = u;
  }
}

// -------- combine: out[t] = sum_k fg*valid*y[fe,pos]  (bf16 gather, no atomics) --------
__global__ __launch_bounds__(256) void combine(
    const u16* __restrict__ y, const int* __restrict__ fe,
    const float* __restrict__ fg, const int* __restrict__ posA,
    float* __restrict__ out)
{
  int t = blockIdx.x;
  int d4 = threadIdx.x;                 // 4-element group, 256 per row
  float s0 = 0.f, s1 = 0.f, s2 = 0.f, s3 = 0.f;
  #pragma unroll
  for (int k = 0; k < 3; k++) {
    int a = t * 3 + k;
    int p = posA[a];
    if (p < CAP) {
      float g = fg[a];
      uint2 v = *(const uint2*)(y + ((size_t)fe[a] * CAP + p) * DDIM + d4 * 4);
      s0 += g * bf2f((u16)(v.x & 0xffff));
      s1 += g * bf2f((u16)(v.x >> 16));
      s2 += g * bf2f((u16)(v.y & 0xffff));
      s3 += g * bf2f((u16)(v.y >> 16));
    }
  }
  float4 r; r.x = s0; r.y = s1; r.z = s2; r.w = s3;
  *(float4*)(out + (size_t)t * DDIM + d4 * 4) = r;
}

// ---------------- expert GEMM: BM=256, BN=64, BK=64, 4 waves, 3 blocks/CU ----------------
// R14 schedule (own-band A staging + mid-phase GLDS_A(t+1) + counted vmcnt),
// narrowed to BN=64: acc 64 AGPR, brB4 16 VGPR, LDS 41KB -> launch_bounds(256,3)
// = 3 independent phase machines per CU for HBM stream/compute overlap.
// EPI==1: h = gelu(A*W1+b1) -> bf16.  EPI==2: y = A*W2+b2 -> bf16.
template<int KTOT, int NTOT, int EPI>
__global__ __launch_bounds__(256, 3) void moe_gemm(
    const u16* __restrict__ Abuf, const float* __restrict__ W,
    const float* __restrict__ bias, u16* __restrict__ hout,
    u16* __restrict__ yout, const int* __restrict__ cnt, int g0)
{
  constexpr int NCT = NTOT / 64;
  constexpr int NT  = KTOT / 64;
  int NB = gridDim.x;
  int b = blockIdx.x;
  int L = (b & 7) * (NB >> 3) + (b >> 3);   // XCD-bijective swizzle (NB % 8 == 0)
  int tcol = L % NCT;
  int rt   = (L / NCT) & 1;
  int el   = L / (NCT * 2);
  int e    = g0 + el;
  int cnte = cnt[e];
  int c0   = rt * 256;
  if (c0 >= cnte) return;
  int n0 = tcol * 64;

  int tid = threadIdx.x, l = tid & 63, w = tid >> 6;

  __shared__ char AsB[256 * 128];   // [256 rows][64 bf16]; band w = rows w*64..+63
  __shared__ char BsB[64 * 136];    // [64 n][64+4 bf16] K-major transposed

  const u16* Arows = Abuf + ((size_t)((EPI == 1 ? e : el)) * CAP + c0) * (size_t)KTOT;
  const float* We = W + (size_t)e * KTOT * NTOT;

  // per-thread B staging: n4 = tid&15 (float4 col group), rows kb = (tid>>4)*4
  int bn4 = tid & 15, bkb = (tid >> 4) * 4;
  const float* Wt = We + (size_t)bkb * NTOT + n0 + bn4 * 4;
  char* BsW = BsB + (bn4 * 4) * 136 + bkb * 2;

  float4 brB4[4];
  #define LOADB(t) { \
    const float* p_ = Wt + (size_t)(t) * 64 * NTOT; \
    _Pragma("unroll") \
    for (int j_ = 0; j_ < 4; j_++) \
      brB4[j_] = *(const float4*)(p_ + (size_t)j_ * NTOT); \
    }
  // col c of the 4-col group: pack rows kb..kb+3 into one b64 K-major write
  #define STOREB() { \
    _Pragma("unroll") \
    for (int c_ = 0; c_ < 4; c_++) { \
      float v0_ = (c_==0?brB4[0].x:c_==1?brB4[0].y:c_==2?brB4[0].z:brB4[0].w); \
      float v1_ = (c_==0?brB4[1].x:c_==1?brB4[1].y:c_==2?brB4[1].z:brB4[1].w); \
      float v2_ = (c_==0?brB4[2].x:c_==1?brB4[2].y:c_==2?brB4[2].z:brB4[2].w); \
      float v3_ = (c_==0?brB4[3].x:c_==1?brB4[3].y:c_==2?brB4[3].z:brB4[3].w); \
      uint2 u_; \
      u_.x = (unsigned)f2bf(v0_) | ((unsigned)f2bf(v1_) << 16); \
      u_.y = (unsigned)f2bf(v2_) | ((unsigned)f2bf(v3_) << 16); \
      *(uint2*)(BsW + c_ * 136) = u_; \
    } }

  // stage wave w's OWN 64-row band: rows w*64 + i*8 + (l>>3)
  #define GLDS_A(t) { \
    _Pragma("unroll") \
    for (int i_ = 0; i_ < 8; i_++) { \
      int rb_ = w * 64 + i_ * 8; \
      int r_  = rb_ + (l >> 3); \
      int cswz_ = (l & 7) ^ (r_ & 7); \
      const char* gsrc_ = (const char*)(Arows + (size_t)r_ * KTOT + (size_t)(t) * 64) + cswz_ * 16; \
      gl_lds16(gsrc_, AsB + rb_ * 128); \
    } }

  #define SB() __builtin_amdgcn_sched_barrier(0)

  f32x4 acc[4][4];
  #pragma unroll
  for (int m = 0; m < 4; m++)
    #pragma unroll
    for (int nn = 0; nn < 4; nn++)
      acc[m][nn] = (f32x4){0.f, 0.f, 0.f, 0.f};

  // prologue: A(0) (own band) + B(0); first STOREB auto-wait drains both once
  GLDS_A(0);
  LOADB(0);

  for (int t = 0; t < NT; ++t) {
    // --- convert+store B(t): auto-wait drains B(t) (A(t) younger only at t=0) ---
    STOREB();
    SB();
    // --- prefetch B(t+1): 4 float4 loads stay in flight across the barrier ---
    if (t + 1 < NT) {
      LOADB(t + 1);
      SB();
      asm volatile("s_waitcnt vmcnt(4)" ::: "memory");    // A(t) drained (old); B(t+1) out
    } else {
      asm volatile("s_waitcnt vmcnt(0)" ::: "memory");    // last iter: drain all
    }
    asm volatile("s_waitcnt lgkmcnt(0)" ::: "memory");    // BsB writes visible
    SB();
    __builtin_amdgcn_s_barrier();
    SB();

    // --- MFMA phase (A frags from own band; A(t+1) issued mid-phase) ---
    {
      // k2 = 0
      s16x8 af[4], bf8[4];
      #pragma unroll
      for (int m = 0; m < 4; m++) {
        int R = w * 64 + m * 16 + (l & 15);
        int sc = (l >> 4) ^ (R & 7);
        af[m] = *(const s16x8*)(AsB + R * 128 + sc * 16);
      }
      #pragma unroll
      for (int nn = 0; nn < 4; nn++) {
        int Nn = nn * 16 + (l & 15);
        int kk = (l >> 4) * 8;
        const char* bp = BsB + Nn * 136 + kk * 2;
        union { s16x8 v8; s16x4 v4[2]; } bu;
        bu.v4[0] = *(const s16x4*)bp;
        bu.v4[1] = *(const s16x4*)(bp + 8);
        bf8[nn] = bu.v8;
      }
      #pragma unroll
      for (int m = 0; m < 4; m++)
        #pragma unroll
        for (int nn = 0; nn < 4; nn++)
          acc[m][nn] = __builtin_amdgcn_mfma_f32_16x16x32_bf16(af[m], bf8[nn], acc[m][nn], 0, 0, 0);

      // k2 = 1: read A frags first, then retire ALL our ds_reads and issue A(t+1)
      #pragma unroll
      for (int m = 0; m < 4; m++) {
        int R = w * 64 + m * 16 + (l & 15);
        int sc = (4 + (l >> 4)) ^ (R & 7);
        af[m] = *(const s16x8*)(AsB + R * 128 + sc * 16);
      }
      if (t + 1 < NT) {
        // all this wave's AsB reads retired -> own band safely rewritable
        asm volatile("s_waitcnt lgkmcnt(0)" ::: "memory");
        GLDS_A(t + 1);
      }
      #pragma unroll
      for (int nn = 0; nn < 4; nn++) {
        int Nn = nn * 16 + (l & 15);
        int kk = 32 + (l >> 4) * 8;
        const char* bp = BsB + Nn * 136 + kk * 2;
        union { s16x8 v8; s16x4 v4[2]; } bu;
        bu.v4[0] = *(const s16x4*)bp;
        bu.v4[1] = *(const s16x4*)(bp + 8);
        bf8[nn] = bu.v8;
      }
      #pragma unroll
      for (int m = 0; m < 4; m++)
        #pragma unroll
        for (int nn = 0; nn < 4; nn++)
          acc[m][nn] = __builtin_amdgcn_mfma_f32_16x16x32_bf16(af[m], bf8[nn], acc[m][nn], 0, 0, 0);
    }
    __builtin_amdgcn_s_barrier();   // BsB reads done before next STOREB
    SB();
  }

  int lr = l >> 4, lc = l & 15;
  float bv[4];
  #pragma unroll
  for (int nn = 0; nn < 4; nn++) bv[nn] = bias[(size_t)e * NTOT + n0 + nn * 16 + lc];

  if (EPI == 1) {
    #pragma unroll
    for (int m = 0; m < 4; m++)
      #pragma unroll
      for (int q = 0; q < 4; q++) {
        int rowL = w * 64 + m * 16 + lr * 4 + q;
        if (c0 + rowL < cnte) {     // clip: rows >= cnte never read usefully
          #pragma unroll
          for (int nn = 0; nn < 4; nn++) {
            float vv = acc[m][nn][q] + bv[nn];
            vv = 0.5f * vv * (1.0f + erff(vv * 0.70710678118f));
            hout[(size_t)(el * CAP + c0 + rowL) * NTOT + (n0 + nn * 16 + lc)] = f2bf(vv);
          }
        }
      }
  } else {
    // bf16 stores into y[e][slot][:]; combine kernel applies gates and sums
    #pragma unroll
    for (int m = 0; m < 4; m++) {
      int rowbase = w * 64 + m * 16 + lr * 4;
      #pragma unroll
      for (int q = 0; q < 4; q++) {
        int slot = c0 + rowbase + q;
        if (slot < cnte) {
          u16* yr = yout + ((size_t)e * CAP + slot) * DDIM + n0;
          #pragma unroll
          for (int nn = 0; nn < 4; nn++)
            yr[nn * 16 + lc] = f2bf(acc[m][nn][q] + bv[nn]);
        }
      }
    }
  }
}

extern "C" void kernel_launch(void* const* d_in, const int* in_sizes, int n_in,
                              void* d_out, int out_size, void* d_ws, size_t ws_size,
                              hipStream_t stream) {
  (void)in_sizes; (void)n_in; (void)ws_size; (void)out_size;
  const float* x  = (const float*)d_in[0];
  const float* gw = (const float*)d_in[1];
  const float* gb = (const float*)d_in[2];
  const float* w1 = (const float*)d_in[3];
  const float* b1 = (const float*)d_in[4];
  const float* w2 = (const float*)d_in[5];
  const float* b2 = (const float*)d_in[6];
  float* out = (float*)d_out;

  char* ws = (char*)d_ws;
  int*   fe   = (int*)(ws);
  float* fg   = (float*)(ws + 49152);
  int*   posA = (int*)(ws + 98304);
  int*   s2a  = (int*)(ws + 147456);
  int*   cnt  = (int*)(ws + 278528);
  u16*   bufA = (u16*)(ws + (1 << 20));
  u16*   hbuf = (u16*)(ws + (1 << 20) + 67108864ull);          // 256 MB slot
  u16*   ybuf = (u16*)(ws + (1 << 20) + 67108864ull + 268435456ull); // 67 MB bf16

  gate_topk<<<TTOK / 8, 512, 0, stream>>>(x, gw, gb, fe, fg);
  scan_pos<<<NEXP, 64, 0, stream>>>(fe, posA, s2a, cnt);
  dispatch<<<NASN, 64, 0, stream>>>(x, fe, posA, bufA);

  moe_gemm<DDIM, HDIM, 1><<<NEXP * 2 * (HDIM / 64), 256, 0, stream>>>(
      bufA, w1, b1, hbuf, nullptr, cnt, 0);
  moe_gemm<HDIM, DDIM, 2><<<NEXP * 2 * (DDIM / 64), 256, 0, stream>>>(
      hbuf, w2, b2, nullptr, ybuf, cnt, 0);

  combine<<<TTOK, 256, 0, stream>>>(ybuf, fe, fg, posA, out);
}

// Round 18
// 661.464 us; speedup vs baseline: 1.1261x; 1.1261x over previous
//
#include <hip/hip_runtime.h>

#define TTOK 4096
#define DDIM 1024
#define HDIM 4096
#define NEXP 64
#define CAP  512
#define NASN (TTOK*3)

typedef unsigned short u16;
typedef __attribute__((ext_vector_type(8))) short s16x8;
typedef __attribute__((ext_vector_type(4))) short s16x4;
typedef __attribute__((ext_vector_type(4))) float f32x4;

__device__ __forceinline__ u16 f2bf(float f) {
  union { float f; unsigned u; } v; v.f = f;
  unsigned u = v.u;
  return (u16)((u + 0x7fffu + ((u >> 16) & 1u)) >> 16);
}

__device__ __forceinline__ float bf2f(u16 h) {
  union { unsigned u; float f; } v; v.u = ((unsigned)h) << 16;
  return v.f;
}

// HW packed conversion: dst = { lo16: bf16(a), hi16: bf16(b) }, RNE (T12 recipe)
__device__ __forceinline__ unsigned cvtpk(float a, float b) {
  unsigned d;
  asm("v_cvt_pk_bf16_f32 %0, %1, %2" : "=v"(d) : "v"(a), "v"(b));
  return d;
}

__device__ __forceinline__ void gl_lds16(const void* g, void* l) {
  __builtin_amdgcn_global_load_lds(
      (const __attribute__((address_space(1))) void*)g,
      (__attribute__((address_space(3))) void*)l, 16, 0, 0);
}

// ---------------- gating: logits + top-3 + softmax ----------------
__global__ __launch_bounds__(512) void gate_topk(
    const float* __restrict__ x, const float* __restrict__ gw,
    const float* __restrict__ gb, int* __restrict__ fe, float* __restrict__ fg)
{
  int lane = threadIdx.x & 63;
  int wid  = threadIdx.x >> 6;
  int t = blockIdx.x * 8 + wid;
  const float* xr = x + (size_t)t * DDIM;
  float acc = gb[lane];
  #pragma unroll 4
  for (int d = 0; d < DDIM; d++) acc += xr[d] * gw[d * NEXP + lane];

  float v = acc;
  float bv[3]; int bi[3];
  #pragma unroll
  for (int j = 0; j < 3; j++) {
    float mv = v; int mi = lane;
    #pragma unroll
    for (int off = 32; off; off >>= 1) {
      float ov = __shfl_xor(mv, off);
      int   oi = __shfl_xor(mi, off);
      if (ov > mv || (ov == mv && oi < mi)) { mv = ov; mi = oi; }
    }
    bv[j] = mv; bi[j] = mi;
    if (lane == mi) v = -3.4e38f;
  }
  if (lane == 0) {
    float e1 = expf(bv[1] - bv[0]), e2 = expf(bv[2] - bv[0]);
    float inv = 1.0f / (1.0f + e1 + e2);
    fe[t*3+0] = bi[0]; fe[t*3+1] = bi[1]; fe[t*3+2] = bi[2];
    fg[t*3+0] = inv;   fg[t*3+1] = e1*inv; fg[t*3+2] = e2*inv;
  }
}

// ------- order-preserving per-expert slot assignment (exact ref semantics) -------
__global__ __launch_bounds__(64) void scan_pos(
    const int* __restrict__ fe, int* __restrict__ posA,
    int* __restrict__ s2a, int* __restrict__ cnt)
{
  int e = blockIdx.x, lane = threadIdx.x;
  int base = 0;
  for (int i0 = 0; i0 < NASN; i0 += 64) {
    int i = i0 + lane;
    bool m = (fe[i] == e);
    unsigned long long bal = __ballot(m);
    int below = __popcll(bal & ((1ull << lane) - 1ull));
    if (m) {
      int p = base + below;
      posA[i] = p;
      if (p < CAP) s2a[e * CAP + p] = i;
    }
    base += __popcll(bal);
  }
  if (lane == 0) cnt[e] = base < CAP ? base : CAP;
}

// ---------------- dispatch: scatter x rows into bf16 expert buffers ----------------
__global__ __launch_bounds__(64) void dispatch(
    const float* __restrict__ x, const int* __restrict__ fe,
    const int* __restrict__ posA, u16* __restrict__ bufA)
{
  int a = blockIdx.x;
  int p = posA[a];
  if (p >= CAP) return;
  int e = fe[a];
  int tok = a / 3;
  int l = threadIdx.x;
  const float4* xr = (const float4*)(x + (size_t)tok * DDIM);
  u16* dst = bufA + ((size_t)e * CAP + p) * DDIM;
  #pragma unroll
  for (int j = 0; j < 4; j++) {
    float4 v = xr[j * 64 + l];
    uint2 u;
    u.x = (unsigned)f2bf(v.x) | ((unsigned)f2bf(v.y) << 16);
    u.y = (unsigned)f2bf(v.z) | ((unsigned)f2bf(v.w) << 16);
    *(uint2*)(dst + (size_t)(j * 64 + l) * 4) = u;
  }
}

// -------- combine: out[t] = sum_k fg*valid*y[fe,pos]  (bf16 gather, no atomics) --------
__global__ __launch_bounds__(256) void combine(
    const u16* __restrict__ y, const int* __restrict__ fe,
    const float* __restrict__ fg, const int* __restrict__ posA,
    float* __restrict__ out)
{
  int t = blockIdx.x;
  int d4 = threadIdx.x;                 // 4-element group, 256 per row
  float s0 = 0.f, s1 = 0.f, s2 = 0.f, s3 = 0.f;
  #pragma unroll
  for (int k = 0; k < 3; k++) {
    int a = t * 3 + k;
    int p = posA[a];
    if (p < CAP) {
      float g = fg[a];
      uint2 v = *(const uint2*)(y + ((size_t)fe[a] * CAP + p) * DDIM + d4 * 4);
      s0 += g * bf2f((u16)(v.x & 0xffff));
      s1 += g * bf2f((u16)(v.x >> 16));
      s2 += g * bf2f((u16)(v.y & 0xffff));
      s3 += g * bf2f((u16)(v.y >> 16));
    }
  }
  float4 r; r.x = s0; r.y = s1; r.z = s2; r.w = s3;
  *(float4*)(out + (size_t)t * DDIM + d4 * 4) = r;
}

// ---------------- expert GEMM: BM=256, BN=128, BK=64, 4 waves (R16 base) ----------------
// Own-band A staging + mid-phase GLDS_A(t+1). B path: float4 loads + counted-vmcnt,
// K-major LDS; STOREB conversion via v_cvt_pk_bf16_f32 (8x fewer VALU insts).
// EPI==1: h = gelu(A*W1+b1) -> bf16.  EPI==2: y = A*W2+b2 -> bf16.
template<int KTOT, int NTOT, int EPI>
__global__ __launch_bounds__(256, 2) void moe_gemm(
    const u16* __restrict__ Abuf, const float* __restrict__ W,
    const float* __restrict__ bias, u16* __restrict__ hout,
    u16* __restrict__ yout, const int* __restrict__ cnt, int g0)
{
  constexpr int NCT = NTOT / 128;
  constexpr int NT  = KTOT / 64;
  int NB = gridDim.x;
  int b = blockIdx.x;
  int L = (b & 7) * (NB >> 3) + (b >> 3);   // XCD-bijective swizzle (NB % 8 == 0)
  int tcol = L % NCT;
  int rt   = (L / NCT) & 1;
  int el   = L / (NCT * 2);
  int e    = g0 + el;
  int cnte = cnt[e];
  int c0   = rt * 256;
  if (c0 >= cnte) return;
  int n0 = tcol * 128;

  int tid = threadIdx.x, l = tid & 63, w = tid >> 6;

  __shared__ char AsB[256 * 128];   // [256 rows][64 bf16]; band w = rows w*64..+63
  __shared__ char BsB[128 * 136];   // [128 n][64+4 bf16] K-major transposed

  const u16* Arows = Abuf + ((size_t)((EPI == 1 ? e : el)) * CAP + c0) * (size_t)KTOT;
  const float* We = W + (size_t)e * KTOT * NTOT;

  // per-thread B staging geometry: n4 = tid&31 (float4 col group), kb = (tid>>5)*8
  int bn4 = tid & 31, bkb = (tid >> 5) * 8;
  const float* Wt = We + (size_t)bkb * NTOT + n0 + bn4 * 4;
  char* BsW = BsB + (bn4 * 4) * 136 + bkb * 2;

  float4 brB4[8];
  #define LOADB(t) { \
    const float* p_ = Wt + (size_t)(t) * 64 * NTOT; \
    _Pragma("unroll") \
    for (int j_ = 0; j_ < 8; j_++) \
      brB4[j_] = *(const float4*)(p_ + (size_t)j_ * NTOT); \
    }
  // per column c: pack rows kb..kb+7 via HW v_cvt_pk_bf16_f32 (RNE, same as f2bf)
  #define STOREB() { \
    _Pragma("unroll") \
    for (int c_ = 0; c_ < 4; c_++) { \
      float v0_ = (c_==0?brB4[0].x:c_==1?brB4[0].y:c_==2?brB4[0].z:brB4[0].w); \
      float v1_ = (c_==0?brB4[1].x:c_==1?brB4[1].y:c_==2?brB4[1].z:brB4[1].w); \
      float v2_ = (c_==0?brB4[2].x:c_==1?brB4[2].y:c_==2?brB4[2].z:brB4[2].w); \
      float v3_ = (c_==0?brB4[3].x:c_==1?brB4[3].y:c_==2?brB4[3].z:brB4[3].w); \
      float v4_ = (c_==0?brB4[4].x:c_==1?brB4[4].y:c_==2?brB4[4].z:brB4[4].w); \
      float v5_ = (c_==0?brB4[5].x:c_==1?brB4[5].y:c_==2?brB4[5].z:brB4[5].w); \
      float v6_ = (c_==0?brB4[6].x:c_==1?brB4[6].y:c_==2?brB4[6].z:brB4[6].w); \
      float v7_ = (c_==0?brB4[7].x:c_==1?brB4[7].y:c_==2?brB4[7].z:brB4[7].w); \
      uint2 ua_, ub_; \
      ua_.x = cvtpk(v0_, v1_); \
      ua_.y = cvtpk(v2_, v3_); \
      ub_.x = cvtpk(v4_, v5_); \
      ub_.y = cvtpk(v6_, v7_); \
      *(uint2*)(BsW + c_ * 136) = ua_; \
      *(uint2*)(BsW + c_ * 136 + 8) = ub_; \
    } }

  // stage wave w's OWN 64-row band: rows w*64 + i*8 + (l>>3)
  #define GLDS_A(t) { \
    _Pragma("unroll") \
    for (int i_ = 0; i_ < 8; i_++) { \
      int rb_ = w * 64 + i_ * 8; \
      int r_  = rb_ + (l >> 3); \
      int cswz_ = (l & 7) ^ (r_ & 7); \
      const char* gsrc_ = (const char*)(Arows + (size_t)r_ * KTOT + (size_t)(t) * 64) + cswz_ * 16; \
      gl_lds16(gsrc_, AsB + rb_ * 128); \
    } }

  #define SB() __builtin_amdgcn_sched_barrier(0)

  f32x4 acc[4][8];
  #pragma unroll
  for (int m = 0; m < 4; m++)
    #pragma unroll
    for (int nn = 0; nn < 8; nn++)
      acc[m][nn] = (f32x4){0.f, 0.f, 0.f, 0.f};

  // prologue: A(0) (own band) + B(0); first STOREB auto-wait drains both once
  GLDS_A(0);
  LOADB(0);

  for (int t = 0; t < NT; ++t) {
    // --- convert+store B(t): auto-wait drains B(t) (A(t) younger only at t=0) ---
    STOREB();
    SB();
    // --- prefetch B(t+1): 8 float4 loads stay in flight across the barrier ---
    if (t + 1 < NT) {
      LOADB(t + 1);
      SB();
      asm volatile("s_waitcnt vmcnt(8)" ::: "memory");    // A(t) drained (old); B(t+1) out
    } else {
      asm volatile("s_waitcnt vmcnt(0)" ::: "memory");    // last iter: drain all
    }
    asm volatile("s_waitcnt lgkmcnt(0)" ::: "memory");    // BsB writes visible
    SB();
    __builtin_amdgcn_s_barrier();
    SB();

    // --- MFMA phase (A frags from own band; A(t+1) issued mid-phase) ---
    {
      // k2 = 0
      s16x8 af[4], bf8[8];
      #pragma unroll
      for (int m = 0; m < 4; m++) {
        int R = w * 64 + m * 16 + (l & 15);
        int sc = (l >> 4) ^ (R & 7);
        af[m] = *(const s16x8*)(AsB + R * 128 + sc * 16);
      }
      #pragma unroll
      for (int nn = 0; nn < 8; nn++) {
        int Nn = nn * 16 + (l & 15);
        int kk = (l >> 4) * 8;
        const char* bp = BsB + Nn * 136 + kk * 2;
        union { s16x8 v8; s16x4 v4[2]; } bu;
        bu.v4[0] = *(const s16x4*)bp;
        bu.v4[1] = *(const s16x4*)(bp + 8);
        bf8[nn] = bu.v8;
      }
      #pragma unroll
      for (int m = 0; m < 4; m++)
        #pragma unroll
        for (int nn = 0; nn < 8; nn++)
          acc[m][nn] = __builtin_amdgcn_mfma_f32_16x16x32_bf16(af[m], bf8[nn], acc[m][nn], 0, 0, 0);

      // k2 = 1: read A frags first, then retire ALL our ds_reads and issue A(t+1)
      #pragma unroll
      for (int m = 0; m < 4; m++) {
        int R = w * 64 + m * 16 + (l & 15);
        int sc = (4 + (l >> 4)) ^ (R & 7);
        af[m] = *(const s16x8*)(AsB + R * 128 + sc * 16);
      }
      if (t + 1 < NT) {
        // all this wave's AsB reads retired -> own band safely rewritable
        asm volatile("s_waitcnt lgkmcnt(0)" ::: "memory");
        GLDS_A(t + 1);
      }
      #pragma unroll
      for (int nn = 0; nn < 8; nn++) {
        int Nn = nn * 16 + (l & 15);
        int kk = 32 + (l >> 4) * 8;
        const char* bp = BsB + Nn * 136 + kk * 2;
        union { s16x8 v8; s16x4 v4[2]; } bu;
        bu.v4[0] = *(const s16x4*)bp;
        bu.v4[1] = *(const s16x4*)(bp + 8);
        bf8[nn] = bu.v8;
      }
      #pragma unroll
      for (int m = 0; m < 4; m++)
        #pragma unroll
        for (int nn = 0; nn < 8; nn++)
          acc[m][nn] = __builtin_amdgcn_mfma_f32_16x16x32_bf16(af[m], bf8[nn], acc[m][nn], 0, 0, 0);
    }
    __builtin_amdgcn_s_barrier();   // BsB reads done before next STOREB
    SB();
  }

  int lr = l >> 4, lc = l & 15;
  float bv[8];
  #pragma unroll
  for (int nn = 0; nn < 8; nn++) bv[nn] = bias[(size_t)e * NTOT + n0 + nn * 16 + lc];

  if (EPI == 1) {
    #pragma unroll
    for (int m = 0; m < 4; m++)
      #pragma unroll
      for (int q = 0; q < 4; q++) {
        int rowL = w * 64 + m * 16 + lr * 4 + q;
        if (c0 + rowL < cnte) {     // clip: rows >= cnte never read usefully
          #pragma unroll
          for (int nn = 0; nn < 8; nn++) {
            float vv = acc[m][nn][q] + bv[nn];
            vv = 0.5f * vv * (1.0f + erff(vv * 0.70710678118f));
            hout[(size_t)(el * CAP + c0 + rowL) * NTOT + (n0 + nn * 16 + lc)] = f2bf(vv);
          }
        }
      }
  } else {
    // bf16 stores into y[e][slot][:]; combine kernel applies gates and sums
    #pragma unroll
    for (int m = 0; m < 4; m++) {
      int rowbase = w * 64 + m * 16 + lr * 4;
      #pragma unroll
      for (int q = 0; q < 4; q++) {
        int slot = c0 + rowbase + q;
        if (slot < cnte) {
          u16* yr = yout + ((size_t)e * CAP + slot) * DDIM + n0;
          #pragma unroll
          for (int nn = 0; nn < 8; nn++)
            yr[nn * 16 + lc] = f2bf(acc[m][nn][q] + bv[nn]);
        }
      }
    }
  }
}

extern "C" void kernel_launch(void* const* d_in, const int* in_sizes, int n_in,
                              void* d_out, int out_size, void* d_ws, size_t ws_size,
                              hipStream_t stream) {
  (void)in_sizes; (void)n_in; (void)ws_size; (void)out_size;
  const float* x  = (const float*)d_in[0];
  const float* gw = (const float*)d_in[1];
  const float* gb = (const float*)d_in[2];
  const float* w1 = (const float*)d_in[3];
  const float* b1 = (const float*)d_in[4];
  const float* w2 = (const float*)d_in[5];
  const float* b2 = (const float*)d_in[6];
  float* out = (float*)d_out;

  char* ws = (char*)d_ws;
  int*   fe   = (int*)(ws);
  float* fg   = (float*)(ws + 49152);
  int*   posA = (int*)(ws + 98304);
  int*   s2a  = (int*)(ws + 147456);
  int*   cnt  = (int*)(ws + 278528);
  u16*   bufA = (u16*)(ws + (1 << 20));
  u16*   hbuf = (u16*)(ws + (1 << 20) + 67108864ull);          // 256 MB slot
  u16*   ybuf = (u16*)(ws + (1 << 20) + 67108864ull + 268435456ull); // 67 MB bf16

  gate_topk<<<TTOK / 8, 512, 0, stream>>>(x, gw, gb, fe, fg);
  scan_pos<<<NEXP, 64, 0, stream>>>(fe, posA, s2a, cnt);
  dispatch<<<NASN, 64, 0, stream>>>(x, fe, posA, bufA);

  moe_gemm<DDIM, HDIM, 1><<<NEXP * 2 * (HDIM / 128), 256, 0, stream>>>(
      bufA, w1, b1, hbuf, nullptr, cnt, 0);
  moe_gemm<HDIM, DDIM, 2><<<NEXP * 2 * (DDIM / 128), 256, 0, stream>>>(
      hbuf, w2, b2, nullptr, ybuf, cnt, 0);

  combine<<<TTOK, 256, 0, stream>>>(ybuf, fe, fg, posA, out);
}